// Round 6
// baseline (42270.892 us; speedup 1.0000x reference)
//
#include <hip/hip_runtime.h>
#include <math.h>

// ---------------------------------------------------------------------------
// SimAM-CNN + Mogrifier-LSTM (Round 6): fence-free persistent LSTM, v2.
//  - gates phase does FULL-K (wih 4096 + whh 256) with all 4 gates per block
//    and fused cell update (c in registers) -> no gslab, no hfin phase.
//  - xm stored bf16 (halves LLC traffic on the most-amplified structure).
//  - 512-thread blocks, launch_bounds(512,4) -> <=128 VGPR, 16 waves/CU.
//  - 7 grid barriers/step (was 8), 16-counter relaxed-atomic barrier.
// xl[b,t,:] = z + b*524288 + t*4096 (flat NCHW reinterpret).
// ---------------------------------------------------------------------------

typedef unsigned short u16;
typedef unsigned int u32;
typedef unsigned long long u64;

#define EPSBN 1e-5f

__device__ __forceinline__ float sigf(float x) { return 1.0f / (1.0f + expf(-x)); }

__device__ __forceinline__ float b2f(u16 u) {
  union { u32 i; float f; } v; v.i = ((u32)u) << 16; return v.f;
}
__device__ __forceinline__ u16 f2b(float f) {
  union { float f; u32 i; } v; v.f = f;
  u32 r = v.i + 0x7FFFu + ((v.i >> 16) & 1u);
  return (u16)(r >> 16);
}

template <typename T> __device__ __forceinline__ float ld1(const T* p);
template <> __device__ __forceinline__ float ld1<float>(const float* p) { return *p; }
template <> __device__ __forceinline__ float ld1<u16>(const u16* p) { return b2f(*p); }
template <typename T> __device__ __forceinline__ void st1(T* p, float v);
template <> __device__ __forceinline__ void st1<float>(float* p, float v) { *p = v; }
template <> __device__ __forceinline__ void st1<u16>(u16* p, float v) { *p = f2b(v); }

template <typename T> __device__ __forceinline__ float2 ld2p(const T* p);
template <> __device__ __forceinline__ float2 ld2p<float>(const float* p) {
  return *(const float2*)p;
}
template <> __device__ __forceinline__ float2 ld2p<u16>(const u16* p) {
  u32 u = *(const u32*)p;
  return make_float2(b2f((u16)(u & 0xffffu)), b2f((u16)(u >> 16)));
}

// ---- agent-scope (sc0 sc1) path: LLC-coherent, bypasses L1/L2 ----
__device__ __forceinline__ float ld_sc(const float* p) {
  return __hip_atomic_load(p, __ATOMIC_RELAXED, __HIP_MEMORY_SCOPE_AGENT);
}
__device__ __forceinline__ void st_sc(float* p, float v) {
  __hip_atomic_store(p, v, __ATOMIC_RELAXED, __HIP_MEMORY_SCOPE_AGENT);
}
__device__ __forceinline__ float2 ld_sc2(const float* p) {
  union { u64 u; float2 f; } v;
  v.u = __hip_atomic_load((const u64*)p, __ATOMIC_RELAXED,
                          __HIP_MEMORY_SCOPE_AGENT);
  return v.f;
}
__device__ __forceinline__ u32 ld_sc_u32(const u16* p) {
  return __hip_atomic_load((const u32*)p, __ATOMIC_RELAXED,
                           __HIP_MEMORY_SCOPE_AGENT);
}
__device__ __forceinline__ void st_sc_u32(u16* p, u32 v) {
  __hip_atomic_store((u32*)p, v, __ATOMIC_RELAXED, __HIP_MEMORY_SCOPE_AGENT);
}
__device__ __forceinline__ u64 ld_sc_u64(const u16* p) {
  return __hip_atomic_load((const u64*)p, __ATOMIC_RELAXED,
                           __HIP_MEMORY_SCOPE_AGENT);
}
__device__ __forceinline__ float2 upk2(u32 u) {
  return make_float2(b2f((u16)(u & 0xffffu)), b2f((u16)(u >> 16)));
}
__device__ __forceinline__ float4 upk4(u64 v) {
  return make_float4(b2f((u16)v), b2f((u16)(v >> 16)), b2f((u16)(v >> 32)),
                     b2f((u16)(v >> 48)));
}
__device__ __forceinline__ u32 pk2(float a, float b) {
  return (u32)f2b(a) | ((u32)f2b(b) << 16);
}

__device__ __forceinline__ float dot4(float4 a, float4 b) {
  return a.x * b.x + a.y * b.y + a.z * b.z + a.w * b.w;
}

__device__ __forceinline__ float simam_elem(float xv, float s, float ss) {
  float mu = (s - xv) * (1.0f / 8191.0f);
  float var = (ss - xv * xv - 8191.0f * mu * mu) * (1.0f / 8190.0f);
  float einv = ((xv - mu) * (xv - mu) + 2.0f * var + 0.2f) / (4.0f * (var + 0.1f));
  return xv * sigf(einv);
}

// --------------------------- CNN stage 1 (R2-verified) ----------------------
__global__ __launch_bounds__(256) void k_conv1(
    const float* __restrict__ x,
    const float* __restrict__ w1a, const float* __restrict__ b1a,
    const float* __restrict__ g1a, const float* __restrict__ bb1a,
    const float* __restrict__ m1a, const float* __restrict__ v1a,
    const float* __restrict__ w1b, const float* __restrict__ b1b,
    const float* __restrict__ g1b, const float* __restrict__ bb1b,
    const float* __restrict__ m1b, const float* __restrict__ v1b,
    u16* __restrict__ y1u, float* __restrict__ ps1, float* __restrict__ pss1)
{
  __shared__ float xs[6][66];
  __shared__ float a1[32][6][66];
  __shared__ float A1[32], T1[32], S2[32], T2[32];
  __shared__ float reds[4][32], redq[4][32];
  const int tid = threadIdx.x;
  const int b = blockIdx.x, t0 = blockIdx.y * 4;
  if (tid < 32) {
    float s = g1a[tid] * rsqrtf(v1a[tid] + EPSBN);
    A1[tid] = w1a[tid] * s;
    T1[tid] = (b1a[tid] - m1a[tid]) * s + bb1a[tid];
    float s2 = g1b[tid] * rsqrtf(v1b[tid] + EPSBN);
    S2[tid] = s2;
    T2[tid] = (b1b[tid] - m1b[tid]) * s2 + bb1b[tid];
  }
  for (int i = tid; i < 6 * 66; i += 256) {
    int r = i / 66, cc = i - r * 66;
    int t = t0 + r - 1, d = cc - 1;
    float v = 0.f;
    if (t >= 0 && t < 128 && d >= 0 && d < 64) v = x[(b * 128 + t) * 64 + d];
    xs[r][cc] = v;
  }
  __syncthreads();
  for (int i = tid; i < 32 * 6 * 66; i += 256) {
    int c = i / 396;
    int rr = i - c * 396;
    int r = rr / 66, cc = rr - r * 66;
    int t = t0 + r - 1, d = cc - 1;
    float v = 0.f;
    if (t >= 0 && t < 128 && d >= 0 && d < 64)
      v = fmaxf(xs[r][cc] * A1[c] + T1[c], 0.f);
    a1[c][r][cc] = v;
  }
  __syncthreads();
  const int d = tid & 63, tq = tid >> 6, lane = tid & 63;
  float acc[32];
#pragma unroll
  for (int i = 0; i < 32; ++i) acc[i] = 0.f;
#pragma unroll 1
  for (int c1 = 0; c1 < 32; ++c1) {
#pragma unroll
    for (int dt = 0; dt < 3; ++dt) {
      float av0 = a1[c1][tq + dt][d];
      float av1 = a1[c1][tq + dt][d + 1];
      float av2 = a1[c1][tq + dt][d + 2];
#pragma unroll
      for (int c2 = 0; c2 < 32; ++c2) {
        const float* wp = w1b + ((c2 * 32 + c1) * 3 + dt) * 3;  // uniform
        acc[c2] += av0 * wp[0] + av1 * wp[1] + av2 * wp[2];
      }
    }
  }
  const size_t ob = (size_t)b * 32 * 8192 + (size_t)(t0 + tq) * 64 + d;
#pragma unroll
  for (int c2 = 0; c2 < 32; ++c2) {
    float v = fmaxf(acc[c2] * S2[c2] + T2[c2], 0.f);
    y1u[ob + (size_t)c2 * 8192] = f2b(v);
    float s = v, q = v * v;
#pragma unroll
    for (int off = 32; off; off >>= 1) {
      s += __shfl_down(s, off);
      q += __shfl_down(q, off);
    }
    if (lane == 0) { reds[tq][c2] = s; redq[tq][c2] = q; }
  }
  __syncthreads();
  if (tid < 32) {
    float s = (reds[0][tid] + reds[1][tid]) + (reds[2][tid] + reds[3][tid]);
    float q = (redq[0][tid] + redq[1][tid]) + (redq[2][tid] + redq[3][tid]);
    ps1[(size_t)((b * 32 + tid) << 5) + blockIdx.y] = s;
    pss1[(size_t)((b * 32 + tid) << 5) + blockIdx.y] = q;
  }
}

__global__ __launch_bounds__(256) void k_red(
    const float* __restrict__ ps, const float* __restrict__ pss,
    float* __restrict__ stats, int npart, int nplanes)
{
  int p = blockIdx.x * 256 + threadIdx.x;
  if (p >= nplanes) return;
  float s = 0.f, q = 0.f;
  for (int j = 0; j < npart; ++j) {
    s += ps[(size_t)p * npart + j];
    q += pss[(size_t)p * npart + j];
  }
  stats[p] = s;
  stats[nplanes + p] = q;
}

template <typename T>
__global__ __launch_bounds__(256) void k_simam_t(
    T* __restrict__ buf, const float* __restrict__ stats, int nplanes)
{
  const int p = blockIdx.x, tid = threadIdx.x;
  T* base = buf + (size_t)p * 8192;
  const float s = stats[p], ss = stats[nplanes + p];
#pragma unroll 4
  for (int i = 0; i < 32; ++i) {
    int idx = tid + i * 256;
    float v = ld1(base + idx);
    st1(base + idx, simam_elem(v, s, ss));
  }
}

// --------------------------- CNN stage 2 (R2-verified) ----------------------
template <typename ZT>
__global__ __launch_bounds__(256) void k_conv2(
    const u16* __restrict__ y1u,
    const float* __restrict__ w2a, const float* __restrict__ b2a,
    const float* __restrict__ g2a, const float* __restrict__ bb2a,
    const float* __restrict__ m2a, const float* __restrict__ v2a,
    const float* __restrict__ w2b, const float* __restrict__ b2b,
    const float* __restrict__ g2b, const float* __restrict__ bb2b,
    const float* __restrict__ m2b, const float* __restrict__ v2b,
    ZT* __restrict__ z, float* __restrict__ ps2, float* __restrict__ pss2)
{
  __shared__ float y1s[32][4][66];
  __shared__ float a2[64][4][66];
  __shared__ float sA2a[64], sT2a[64], sA2b[64], sT2b[64];
  const int tid = threadIdx.x;
  const int t0 = blockIdx.x * 2, b = blockIdx.y;
  if (tid < 64) {
    float sa = g2a[tid] * rsqrtf(v2a[tid] + EPSBN);
    sA2a[tid] = sa;
    sT2a[tid] = (b2a[tid] - m2a[tid]) * sa + bb2a[tid];
    float sb = g2b[tid] * rsqrtf(v2b[tid] + EPSBN);
    sA2b[tid] = sb;
    sT2b[tid] = (b2b[tid] - m2b[tid]) * sb + bb2b[tid];
  }
  for (int i = tid; i < 32 * 4 * 66; i += 256) {
    int c1 = i / 264;
    int rr = i - c1 * 264;
    int r = rr / 66, cc = rr - r * 66;
    int t = t0 + r - 1, dd = cc - 1;
    float v = 0.f;
    if (t >= 0 && t < 128 && dd >= 0 && dd < 64)
      v = b2f(y1u[(size_t)(b * 32 + c1) * 8192 + t * 64 + dd]);
    y1s[c1][r][cc] = v;
  }
  __syncthreads();
  const int lane = tid & 63;
  const int c2base = __builtin_amdgcn_readfirstlane((int)(tid >> 6)) * 16;
#pragma unroll 1
  for (int i = 0; i < 16; ++i) {
    const int c2 = c2base + i;
    const float* wp = w2a + c2 * 32;  // uniform
    const float scl = sA2a[c2], off = sT2a[c2];
#pragma unroll 1
    for (int r = 0; r < 4; ++r) {
      for (int cc = lane; cc < 66; cc += 64) {
        float acc = 0.f;
#pragma unroll
        for (int c1 = 0; c1 < 32; ++c1) acc += y1s[c1][r][cc] * wp[c1];
        int t = t0 + r - 1, dd = cc - 1;
        float val = 0.f;
        if (t >= 0 && t < 128 && dd >= 0 && dd < 64)
          val = fmaxf(acc * scl + off, 0.f);
        a2[c2][r][cc] = val;
      }
    }
  }
  __syncthreads();
  const int d = tid & 63;
  const int gq = __builtin_amdgcn_readfirstlane((int)(tid >> 6));
  float acc[16][2];
#pragma unroll
  for (int i = 0; i < 16; ++i) { acc[i][0] = 0.f; acc[i][1] = 0.f; }
#pragma unroll 1
  for (int c1 = 0; c1 < 64; ++c1) {
    float a00 = a2[c1][0][d], a01 = a2[c1][0][d + 1], a02 = a2[c1][0][d + 2];
    float a10 = a2[c1][1][d], a11 = a2[c1][1][d + 1], a12 = a2[c1][1][d + 2];
    float a20 = a2[c1][2][d], a21 = a2[c1][2][d + 1], a22 = a2[c1][2][d + 2];
    float a30 = a2[c1][3][d], a31 = a2[c1][3][d + 1], a32 = a2[c1][3][d + 2];
#pragma unroll
    for (int i = 0; i < 16; ++i) {
      const float* wp = w2b + (size_t)((gq * 16 + i) * 64 + c1) * 9;  // uniform
      float w0 = wp[0], w1 = wp[1], w2 = wp[2];
      float w3 = wp[3], w4 = wp[4], w5 = wp[5];
      float w6 = wp[6], w7 = wp[7], w8 = wp[8];
      acc[i][0] += a00 * w0 + a01 * w1 + a02 * w2 + a10 * w3 + a11 * w4 +
                   a12 * w5 + a20 * w6 + a21 * w7 + a22 * w8;
      acc[i][1] += a10 * w0 + a11 * w1 + a12 * w2 + a20 * w3 + a21 * w4 +
                   a22 * w5 + a30 * w6 + a31 * w7 + a32 * w8;
    }
  }
#pragma unroll
  for (int i = 0; i < 16; ++i) {
    int c2 = gq * 16 + i;
    float sc = sA2b[c2], tb = sT2b[c2];
    float v0 = fmaxf(acc[i][0] * sc + tb, 0.f);
    float v1 = fmaxf(acc[i][1] * sc + tb, 0.f);
    size_t ob = (size_t)(b * 64 + c2) * 8192 + (size_t)t0 * 64 + d;
    st1(z + ob, v0);
    st1(z + ob + 64, v1);
    float s = v0 + v1, q = v0 * v0 + v1 * v1;
#pragma unroll
    for (int off = 32; off; off >>= 1) {
      s += __shfl_down(s, off);
      q += __shfl_down(q, off);
    }
    if (lane == 0) {
      ps2[(size_t)((b * 64 + c2) << 6) + blockIdx.x] = s;
      pss2[(size_t)((b * 64 + c2) << 6) + blockIdx.x] = q;
    }
  }
}

// --------------------------- persistent LSTM -------------------------------
// Fence-free grid barrier (16 spread counters, relaxed agent atomics).
__device__ __forceinline__ void gridbar(unsigned* cnt, unsigned target) {
  asm volatile("" ::: "memory");
  __syncthreads();
  if (threadIdx.x == 0)
    __hip_atomic_fetch_add(&cnt[(blockIdx.x & 15) * 64], 1u,
                           __ATOMIC_RELAXED, __HIP_MEMORY_SCOPE_AGENT);
  if (threadIdx.x < 64) {
    int lane = threadIdx.x;
    for (;;) {
      unsigned v = 0;
      if (lane < 16)
        v = __hip_atomic_load(&cnt[lane * 64], __ATOMIC_RELAXED,
                              __HIP_MEMORY_SCOPE_AGENT);
      v += __shfl_xor(v, 1);
      v += __shfl_xor(v, 2);
      v += __shfl_xor(v, 4);
      v += __shfl_xor(v, 8);
      v = __shfl(v, 0);
      if (v >= target) break;
      __builtin_amdgcn_s_sleep(2);
    }
  }
  __syncthreads();
  asm volatile("" ::: "memory");
}

// LDS xor swizzles (keep float4 alignment)
__device__ __forceinline__ int sw_q(int col) { return col ^ (((col >> 6) & 3) << 3); }
__device__ __forceinline__ int sw_r(int col) { return col ^ (((col >> 7) & 7) << 2); }
__device__ __forceinline__ int sw_g(int col) { return col ^ (((col >> 8) & 3) << 2); }
__device__ __forceinline__ int sw_h(int col) { return col ^ (((col >> 6) & 3) << 2); }

// q: xm[b,n] = 2*sigmoid(hsrc[b,:256].qw[n,:] + qb[n]) * xin[b,n]
// 512 blocks = 128 n-tiles(32) x 4 b-tiles(32). 512 thr: wave=4b, lane:
// ns(16)x2n, ksub(4) K-split 64. hsrc (fp32 sc) staged in LDS.
template <typename ZT, bool FROMXM>
__device__ __forceinline__ void q_phase(
    const float* __restrict__ qw, const float* __restrict__ qb,
    const float* __restrict__ hsrc, const ZT* __restrict__ zin,
    size_t zstride, const u16* __restrict__ xm_in, u16* __restrict__ xm_out,
    float* __restrict__ smem, int blk, int tid)
{
  const int nt = blk & 127, bt = blk >> 7;
  const int b0 = bt * 32;
  for (int i = tid; i < 4096; i += 512) {
    int row = i >> 7, cp = i & 127;
    float2 v = ld_sc2(hsrc + (size_t)(b0 + row) * 256 + cp * 2);
    *(float2*)&smem[row * 258 + sw_q(cp * 2)] = v;
  }
  __syncthreads();
  const int lane = tid & 63, w = tid >> 6;
  const int ns = lane & 15, ksub = lane >> 4;
  const int n0 = nt * 32 + ns * 2;
  const int bw = b0 + w * 4;
  float acc[2][4];
#pragma unroll
  for (int i = 0; i < 2; ++i)
#pragma unroll
    for (int j = 0; j < 4; ++j) acc[i][j] = 0.f;
  const float* w0p = qw + (size_t)n0 * 256 + ksub * 64;
  const float* w1p = w0p + 256;
#pragma unroll 4
  for (int k = 0; k < 64; k += 4) {
    float4 wa = *(const float4*)(w0p + k);
    float4 wb = *(const float4*)(w1p + k);
    int sc = sw_q(ksub * 64 + k);
#pragma unroll
    for (int j = 0; j < 4; ++j) {
      float4 hv = *(const float4*)&smem[(w * 4 + j) * 258 + sc];
      acc[0][j] += dot4(wa, hv);
      acc[1][j] += dot4(wb, hv);
    }
  }
#pragma unroll
  for (int i = 0; i < 2; ++i)
#pragma unroll
    for (int j = 0; j < 4; ++j) {
      acc[i][j] += __shfl_xor(acc[i][j], 16);
      acc[i][j] += __shfl_xor(acc[i][j], 32);
    }
  if (ksub == 0) {
    float bq0 = qb[n0], bq1 = qb[n0 + 1];
#pragma unroll
    for (int j = 0; j < 4; ++j) {
      size_t bi = (size_t)(bw + j);
      float2 xv;
      if (FROMXM) xv = upk2(ld_sc_u32(xm_in + bi * 4096 + n0));
      else        xv = ld2p(zin + bi * zstride + n0);
      st_sc_u32(xm_out + bi * 4096 + n0,
                pk2(2.f * sigf(acc[0][j] + bq0) * xv.x,
                    2.f * sigf(acc[1][j] + bq1) * xv.y));
    }
  }
}

// r: hm[b,n] = 2*sigmoid(xm[b,:4096].rw[n,:] + rb[n]) * src[b,n]
// 512 blocks = 32 n-tiles(8) x 16 b-tiles(8). thread: wave=n, lane: b(8),
// ksub(8) K-split; xm (bf16) staged per 1024-chunk in LDS.
__device__ __forceinline__ void r_phase(
    const float* __restrict__ rw, const float* __restrict__ rb,
    const float* __restrict__ src, const u16* __restrict__ xm,
    float* __restrict__ hm, float* __restrict__ smem, int blk, int tid)
{
  const int nt = blk & 31, bt = blk >> 5;
  const int n0t = nt * 8, b0 = bt * 8;
  const int lane = tid & 63, w = tid >> 6;
  const int bl = lane & 7, ksub = (lane >> 3) & 7;
  const int n = n0t + w;
  float acc = 0.f;
  const float* wr = rw + (size_t)n * 4096;
#pragma unroll 1
  for (int c = 0; c < 4; ++c) {
    __syncthreads();
    for (int i = tid; i < 2048; i += 512) {
      int row = i >> 8, qd = i & 255;
      float4 v = upk4(ld_sc_u64(xm + (size_t)(b0 + row) * 4096 + c * 1024 + qd * 4));
      *(float4*)&smem[row * 1032 + sw_r(qd * 4)] = v;
    }
    __syncthreads();
    const float* wc = wr + c * 1024 + ksub * 128;
#pragma unroll 4
    for (int k = 0; k < 128; k += 4) {
      int sc = sw_r(ksub * 128 + k);
      float4 xv = *(const float4*)&smem[bl * 1032 + sc];
      float4 wv = *(const float4*)(wc + k);
      acc += dot4(wv, xv);
    }
  }
  acc += __shfl_xor(acc, 8);
  acc += __shfl_xor(acc, 16);
  acc += __shfl_xor(acc, 32);
  if (ksub == 0) {
    int idx = (b0 + bl) * 256 + n;
    float sv = ld_sc(src + idx);
    st_sc(hm + idx, 2.f * sigf(acc + rb[n]) * sv);
  }
}

// gates: full-K (wih 4096 + whh 256), fused cell update.
// 512 blocks = 16 kk-tiles(16) x 32 b-tiles(4). Rows: 64 = 4 gates x 16 kk.
// thread: ksub = tid&3 (K-split), bp = (tid>>2)&1 (2 b each), row = tid>>3.
__device__ __forceinline__ void g_phase(
    const float* __restrict__ wih, const float* __restrict__ whh,
    const u16* __restrict__ xm, const float* __restrict__ hm,
    float* __restrict__ h, float& c_reg,
    float bi_i, float bi_f, float bi_g, float bi_o,
    float* __restrict__ smem, int blk, int tid)
{
  const int kt = blk & 15, bt = blk >> 4;
  const int b0 = bt * 4;
  const int ksub = tid & 3, bp = (tid >> 2) & 1, row = tid >> 3;
  const int gate = row >> 4, kkl = row & 15;
  const int grow = gate * 256 + kt * 16 + kkl;
  float* gatelds = smem + 8256;  // [64][4]
  float acc0 = 0.f, acc1 = 0.f;
  const float* wr = wih + (size_t)grow * 4096;
#pragma unroll 1
  for (int c = 0; c < 4; ++c) {
    __syncthreads();
    for (int i = tid; i < 1024; i += 512) {
      int r = i >> 8, qd = i & 255;
      float4 v = upk4(ld_sc_u64(xm + (size_t)(b0 + r) * 4096 + c * 1024 + qd * 4));
      *(float4*)&smem[r * 1040 + sw_g(qd * 4)] = v;
    }
    __syncthreads();
    const float* wc = wr + c * 1024 + ksub * 256;
#pragma unroll 4
    for (int k = 0; k < 256; k += 4) {
      int sc = sw_g(ksub * 256 + k);
      float4 wv = *(const float4*)(wc + k);
      float4 x0 = *(const float4*)&smem[(bp * 2 + 0) * 1040 + sc];
      float4 x1 = *(const float4*)&smem[(bp * 2 + 1) * 1040 + sc];
      acc0 += dot4(wv, x0);
      acc1 += dot4(wv, x1);
    }
  }
  // whh contribution (K=256 over hm, fp32 sc)
  __syncthreads();
  for (int i = tid; i < 512; i += 512) {
    int r = i >> 7, cp = i & 127;
    float2 v = ld_sc2(hm + (size_t)(b0 + r) * 256 + cp * 2);
    *(float2*)&smem[r * 264 + sw_h(cp * 2)] = v;
  }
  __syncthreads();
  {
    const float* vr = whh + (size_t)grow * 256 + ksub * 64;
#pragma unroll 4
    for (int k = 0; k < 64; k += 4) {
      int sc = sw_h(ksub * 64 + k);
      float4 wv = *(const float4*)(vr + k);
      float4 x0 = *(const float4*)&smem[(bp * 2 + 0) * 264 + sc];
      float4 x1 = *(const float4*)&smem[(bp * 2 + 1) * 264 + sc];
      acc0 += dot4(wv, x0);
      acc1 += dot4(wv, x1);
    }
  }
  acc0 += __shfl_xor(acc0, 1);
  acc0 += __shfl_xor(acc0, 2);
  acc1 += __shfl_xor(acc1, 1);
  acc1 += __shfl_xor(acc1, 2);
  __syncthreads();
  if (ksub == 0) {
    gatelds[row * 4 + bp * 2 + 0] = acc0;
    gatelds[row * 4 + bp * 2 + 1] = acc1;
  }
  __syncthreads();
  if (tid < 64) {
    int kk2 = tid & 15, blc = tid >> 4;
    float gi = gatelds[(kk2) * 4 + blc] + bi_i;
    float gf = gatelds[(16 + kk2) * 4 + blc] + bi_f;
    float gg = gatelds[(32 + kk2) * 4 + blc] + bi_g;
    float go = gatelds[(48 + kk2) * 4 + blc] + bi_o;
    float cn = sigf(gf) * c_reg + sigf(gi) * tanhf(gg);
    c_reg = cn;
    st_sc(h + (b0 + blc) * 256 + kt * 16 + kk2, sigf(go) * tanhf(cn));
  }
}

template <typename ZT>
__global__ __launch_bounds__(512, 4) void k_lstm(
    const ZT* __restrict__ z,
    const float* __restrict__ q0w, const float* __restrict__ q0b,
    const float* __restrict__ r0w, const float* __restrict__ r0b,
    const float* __restrict__ q1w, const float* __restrict__ q1b,
    const float* __restrict__ r1w, const float* __restrict__ r1b,
    const float* __restrict__ q2w, const float* __restrict__ q2b,
    const float* __restrict__ r2w, const float* __restrict__ r2b,
    const float* __restrict__ wih, const float* __restrict__ whh,
    const float* __restrict__ bih, const float* __restrict__ bhh,
    const float* __restrict__ fcw, const float* __restrict__ fcb,
    u16* __restrict__ xm, float* __restrict__ h, float* __restrict__ hm,
    unsigned* __restrict__ cnt, float* __restrict__ out)
{
  __shared__ float smem[8520];  // 34,080 B; q 32x258 / r 8x1032 / g 4x1040+gates
  const int blk = blockIdx.x, tid = threadIdx.x;
  // gate bias preload + cell register (threads 0..63 of each g-role block)
  float bi_i = 0.f, bi_f = 0.f, bi_g = 0.f, bi_o = 0.f, c_reg = 0.f;
  {
    const int kt = blk & 15;
    if (tid < 64) {
      int gk = kt * 16 + (tid & 15);
      bi_i = bih[gk] + bhh[gk];
      bi_f = bih[gk + 256] + bhh[gk + 256];
      bi_g = bih[gk + 512] + bhh[gk + 512];
      bi_o = bih[gk + 768] + bhh[gk + 768];
    }
  }
  unsigned ep = 0;
#pragma unroll 1
  for (int t = 0; t < 128; ++t) {
    q_phase<ZT, false>(q0w, q0b, h, z + (size_t)t * 4096, 524288, xm, xm,
                       smem, blk, tid);
    gridbar(cnt, (++ep) * 512u);
    r_phase(r0w, r0b, h, xm, hm, smem, blk, tid);
    gridbar(cnt, (++ep) * 512u);
    q_phase<ZT, true>(q1w, q1b, hm, (const ZT*)0, 0, xm, xm, smem, blk, tid);
    gridbar(cnt, (++ep) * 512u);
    r_phase(r1w, r1b, hm, xm, hm, smem, blk, tid);
    gridbar(cnt, (++ep) * 512u);
    q_phase<ZT, true>(q2w, q2b, hm, (const ZT*)0, 0, xm, xm, smem, blk, tid);
    gridbar(cnt, (++ep) * 512u);
    r_phase(r2w, r2b, hm, xm, hm, smem, blk, tid);
    gridbar(cnt, (++ep) * 512u);
    g_phase(wih, whh, xm, hm, h, c_reg, bi_i, bi_f, bi_g, bi_o, smem, blk, tid);
    gridbar(cnt, (++ep) * 512u);
  }
  if (blk < 128 && tid < 5) {
    float acc = fcb[tid];
    const float* hr = h + blk * 256;
    const float* wr = fcw + (size_t)tid * 256;
    for (int k = 0; k < 256; ++k) acc += ld_sc(hr + k) * wr[k];
    out[blk * 5 + tid] = acc;
  }
}

__global__ __launch_bounds__(256) void k_report(float* out, float v, int n) {
  int i = blockIdx.x * 256 + threadIdx.x;
  if (i < n) out[i] = v;
}

// ---------------------------------------------------------------------------
struct Net {
  const float *x;
  const float *c1a_w, *c1a_b, *g1a, *b1a, *m1a, *v1a;
  const float *c1b_w, *c1b_b, *g1b, *b1b, *m1b, *v1b;
  const float *c2a_w, *c2a_b, *g2a, *b2a, *m2a, *v2a;
  const float *c2b_w, *c2b_b, *g2b, *b2b, *m2b, *v2b;
  const float *qw[3], *qb[3], *rw[3], *rb[3];
  const float *wih, *whh, *bih, *bhh, *fcw, *fcb;
};

template <typename ZT>
static void run_all(const Net& p, ZT* z, u16* y1u, char* scr,
                    float* ps1, float* pss1, float* st1v,
                    float* ps2, float* pss2, float* st2v,
                    float* out, hipStream_t stream)
{
  u16* xm   = (u16*)scr;                       // 1,048,576 B
  float* h  = (float*)(scr + 1048576);         // 131,072 B
  float* hm = (float*)(scr + 1179648);         // 131,072 B
  unsigned* cnt = (unsigned*)(scr + 1310720);  // 16 counters, 256B apart

  k_conv1<<<dim3(128, 32), 256, 0, stream>>>(p.x, p.c1a_w, p.c1a_b, p.g1a,
      p.b1a, p.m1a, p.v1a, p.c1b_w, p.c1b_b, p.g1b, p.b1b, p.m1b, p.v1b,
      y1u, ps1, pss1);
  k_red<<<16, 256, 0, stream>>>(ps1, pss1, st1v, 32, 4096);
  k_simam_t<u16><<<4096, 256, 0, stream>>>(y1u, st1v, 4096);
  k_conv2<ZT><<<dim3(64, 128), 256, 0, stream>>>(y1u, p.c2a_w, p.c2a_b, p.g2a,
      p.b2a, p.m2a, p.v2a, p.c2b_w, p.c2b_b, p.g2b, p.b2b, p.m2b, p.v2b,
      z, ps2, pss2);
  k_red<<<32, 256, 0, stream>>>(ps2, pss2, st2v, 64, 8192);
  k_simam_t<ZT><<<8192, 256, 0, stream>>>(z, st2v, 8192);

  hipMemsetAsync(h, 0, 131072, stream);                 // h(t=0) = 0
  hipMemsetAsync(cnt, 0, 16 * 64 * sizeof(unsigned), stream);

  k_lstm<ZT><<<512, 512, 0, stream>>>(z,
      p.qw[0], p.qb[0], p.rw[0], p.rb[0],
      p.qw[1], p.qb[1], p.rw[1], p.rb[1],
      p.qw[2], p.qb[2], p.rw[2], p.rb[2],
      p.wih, p.whh, p.bih, p.bhh, p.fcw, p.fcb,
      xm, h, hm, cnt, out);
}

extern "C" void kernel_launch(void* const* d_in, const int* in_sizes, int n_in,
                              void* d_out, int out_size, void* d_ws, size_t ws_size,
                              hipStream_t stream)
{
  (void)in_sizes; (void)n_in;
  Net p;
  p.x = (const float*)d_in[0];
  p.c1a_w = (const float*)d_in[1];  p.c1a_b = (const float*)d_in[2];
  p.g1a = (const float*)d_in[3];    p.b1a = (const float*)d_in[4];
  p.m1a = (const float*)d_in[5];    p.v1a = (const float*)d_in[6];
  p.c1b_w = (const float*)d_in[7];  p.c1b_b = (const float*)d_in[8];
  p.g1b = (const float*)d_in[9];    p.b1b = (const float*)d_in[10];
  p.m1b = (const float*)d_in[11];   p.v1b = (const float*)d_in[12];
  p.c2a_w = (const float*)d_in[13]; p.c2a_b = (const float*)d_in[14];
  p.g2a = (const float*)d_in[15];   p.b2a = (const float*)d_in[16];
  p.m2a = (const float*)d_in[17];   p.v2a = (const float*)d_in[18];
  p.c2b_w = (const float*)d_in[19]; p.c2b_b = (const float*)d_in[20];
  p.g2b = (const float*)d_in[21];   p.b2b = (const float*)d_in[22];
  p.m2b = (const float*)d_in[23];   p.v2b = (const float*)d_in[24];
  for (int i = 0; i < 3; ++i) {
    p.qw[i] = (const float*)d_in[25 + 4 * i];
    p.qb[i] = (const float*)d_in[26 + 4 * i];
    p.rw[i] = (const float*)d_in[27 + 4 * i];
    p.rb[i] = (const float*)d_in[28 + 4 * i];
  }
  p.wih = (const float*)d_in[37]; p.whh = (const float*)d_in[38];
  p.bih = (const float*)d_in[39]; p.bhh = (const float*)d_in[40];
  p.fcw = (const float*)d_in[41]; p.fcb = (const float*)d_in[42];
  float* out = (float*)d_out;
  char* base = (char*)d_ws;

  const size_t ZB_F32 = 268435456, ZB_BF16 = 134217728, Y1B = 67108864;
  const size_t STATS = 1048576 * 2 + 65536 + 2097152 * 2 + 65536;
  const size_t HI_NEED = ZB_F32 + Y1B + STATS;   // ~326 MiB
  const size_t LO_NEED = ZB_BF16 + Y1B + STATS;  // ~198 MiB

  if (ws_size >= HI_NEED) {
    float* z = (float*)base;
    u16* y1u = (u16*)(base + ZB_F32);
    char* scr = base + ZB_F32;  // overlays y1u (dead after conv2)
    char* sb = base + ZB_F32 + Y1B;
    run_all<float>(p, z, y1u, scr,
                   (float*)sb, (float*)(sb + 1048576), (float*)(sb + 2097152),
                   (float*)(sb + 2162688), (float*)(sb + 4259840),
                   (float*)(sb + 6356992), out, stream);
  } else if (ws_size >= LO_NEED) {
    u16* z = (u16*)base;
    u16* y1u = (u16*)(base + ZB_BF16);
    char* scr = base + ZB_BF16;  // overlays y1u (dead after conv2)
    char* sb = base + ZB_BF16 + Y1B;
    run_all<u16>(p, z, y1u, scr,
                 (float*)sb, (float*)(sb + 1048576), (float*)(sb + 2097152),
                 (float*)(sb + 2162688), (float*)(sb + 4259840),
                 (float*)(sb + 6356992), out, stream);
  } else {
    k_report<<<3, 256, 0, stream>>>(out, (float)(ws_size >> 20), out_size);
  }
}

// Round 7
// 36935.687 us; speedup vs baseline: 1.1444x; 1.1444x over previous
//
#include <hip/hip_runtime.h>
#include <math.h>

// ---------------------------------------------------------------------------
// SimAM-CNN + Mogrifier-LSTM (Round 7): persistent LSTM with
//  - store-based grid barrier (no atomic RMW contention; per-block epoch slot)
//  - explicit s_waitcnt vmcnt(0) before barrier signal (fixes latent race)
//  - ALL LSTM weights pre-converted to bf16 in ws -> per-XCD L2-resident
//  - h/hm stored bf16 (halves the h-broadcast amplification in q)
// xl[b,t,:] = z + b*524288 + t*4096 (flat NCHW reinterpret).
// ---------------------------------------------------------------------------

typedef unsigned short u16;
typedef unsigned int u32;
typedef unsigned long long u64;

#define EPSBN 1e-5f

__device__ __forceinline__ float sigf(float x) { return 1.0f / (1.0f + expf(-x)); }

__device__ __forceinline__ float b2f(u16 u) {
  union { u32 i; float f; } v; v.i = ((u32)u) << 16; return v.f;
}
__device__ __forceinline__ u16 f2b(float f) {
  union { float f; u32 i; } v; v.f = f;
  u32 r = v.i + 0x7FFFu + ((v.i >> 16) & 1u);
  return (u16)(r >> 16);
}

template <typename T> __device__ __forceinline__ float ld1(const T* p);
template <> __device__ __forceinline__ float ld1<float>(const float* p) { return *p; }
template <> __device__ __forceinline__ float ld1<u16>(const u16* p) { return b2f(*p); }
template <typename T> __device__ __forceinline__ void st1(T* p, float v);
template <> __device__ __forceinline__ void st1<float>(float* p, float v) { *p = v; }
template <> __device__ __forceinline__ void st1<u16>(u16* p, float v) { *p = f2b(v); }

template <typename T> __device__ __forceinline__ float2 ld2p(const T* p);
template <> __device__ __forceinline__ float2 ld2p<float>(const float* p) {
  return *(const float2*)p;
}
template <> __device__ __forceinline__ float2 ld2p<u16>(const u16* p) {
  u32 u = *(const u32*)p;
  return make_float2(b2f((u16)(u & 0xffffu)), b2f((u16)(u >> 16)));
}

// ---- agent-scope (sc0 sc1) path: LLC-coherent, bypasses L1/L2 ----
__device__ __forceinline__ u32 ld_sc_u32(const u16* p) {
  return __hip_atomic_load((const u32*)p, __ATOMIC_RELAXED,
                           __HIP_MEMORY_SCOPE_AGENT);
}
__device__ __forceinline__ void st_sc_u32(u16* p, u32 v) {
  __hip_atomic_store((u32*)p, v, __ATOMIC_RELAXED, __HIP_MEMORY_SCOPE_AGENT);
}
__device__ __forceinline__ u64 ld_sc_u64(const u16* p) {
  return __hip_atomic_load((const u64*)p, __ATOMIC_RELAXED,
                           __HIP_MEMORY_SCOPE_AGENT);
}
__device__ __forceinline__ float2 upk2(u32 u) {
  return make_float2(b2f((u16)(u & 0xffffu)), b2f((u16)(u >> 16)));
}
__device__ __forceinline__ float4 upk4(u64 v) {
  return make_float4(b2f((u16)v), b2f((u16)(v >> 16)), b2f((u16)(v >> 32)),
                     b2f((u16)(v >> 48)));
}
__device__ __forceinline__ u32 pk2(float a, float b) {
  return (u32)f2b(a) | ((u32)f2b(b) << 16);
}
// plain (L2-cacheable) bf16x4 load for read-only ws-resident weights
__device__ __forceinline__ float4 ldw4(const u16* p) {
  return upk4(*(const u64*)p);
}

__device__ __forceinline__ float dot4(float4 a, float4 b) {
  return a.x * b.x + a.y * b.y + a.z * b.z + a.w * b.w;
}

__device__ __forceinline__ float simam_elem(float xv, float s, float ss) {
  float mu = (s - xv) * (1.0f / 8191.0f);
  float var = (ss - xv * xv - 8191.0f * mu * mu) * (1.0f / 8190.0f);
  float einv = ((xv - mu) * (xv - mu) + 2.0f * var + 0.2f) / (4.0f * (var + 0.1f));
  return xv * sigf(einv);
}

// --------------------------- CNN stage 1 (R2-verified) ----------------------
__global__ __launch_bounds__(256) void k_conv1(
    const float* __restrict__ x,
    const float* __restrict__ w1a, const float* __restrict__ b1a,
    const float* __restrict__ g1a, const float* __restrict__ bb1a,
    const float* __restrict__ m1a, const float* __restrict__ v1a,
    const float* __restrict__ w1b, const float* __restrict__ b1b,
    const float* __restrict__ g1b, const float* __restrict__ bb1b,
    const float* __restrict__ m1b, const float* __restrict__ v1b,
    u16* __restrict__ y1u, float* __restrict__ ps1, float* __restrict__ pss1)
{
  __shared__ float xs[6][66];
  __shared__ float a1[32][6][66];
  __shared__ float A1[32], T1[32], S2[32], T2[32];
  __shared__ float reds[4][32], redq[4][32];
  const int tid = threadIdx.x;
  const int b = blockIdx.x, t0 = blockIdx.y * 4;
  if (tid < 32) {
    float s = g1a[tid] * rsqrtf(v1a[tid] + EPSBN);
    A1[tid] = w1a[tid] * s;
    T1[tid] = (b1a[tid] - m1a[tid]) * s + bb1a[tid];
    float s2 = g1b[tid] * rsqrtf(v1b[tid] + EPSBN);
    S2[tid] = s2;
    T2[tid] = (b1b[tid] - m1b[tid]) * s2 + bb1b[tid];
  }
  for (int i = tid; i < 6 * 66; i += 256) {
    int r = i / 66, cc = i - r * 66;
    int t = t0 + r - 1, d = cc - 1;
    float v = 0.f;
    if (t >= 0 && t < 128 && d >= 0 && d < 64) v = x[(b * 128 + t) * 64 + d];
    xs[r][cc] = v;
  }
  __syncthreads();
  for (int i = tid; i < 32 * 6 * 66; i += 256) {
    int c = i / 396;
    int rr = i - c * 396;
    int r = rr / 66, cc = rr - r * 66;
    int t = t0 + r - 1, d = cc - 1;
    float v = 0.f;
    if (t >= 0 && t < 128 && d >= 0 && d < 64)
      v = fmaxf(xs[r][cc] * A1[c] + T1[c], 0.f);
    a1[c][r][cc] = v;
  }
  __syncthreads();
  const int d = tid & 63, tq = tid >> 6, lane = tid & 63;
  float acc[32];
#pragma unroll
  for (int i = 0; i < 32; ++i) acc[i] = 0.f;
#pragma unroll 1
  for (int c1 = 0; c1 < 32; ++c1) {
#pragma unroll
    for (int dt = 0; dt < 3; ++dt) {
      float av0 = a1[c1][tq + dt][d];
      float av1 = a1[c1][tq + dt][d + 1];
      float av2 = a1[c1][tq + dt][d + 2];
#pragma unroll
      for (int c2 = 0; c2 < 32; ++c2) {
        const float* wp = w1b + ((c2 * 32 + c1) * 3 + dt) * 3;  // uniform
        acc[c2] += av0 * wp[0] + av1 * wp[1] + av2 * wp[2];
      }
    }
  }
  const size_t ob = (size_t)b * 32 * 8192 + (size_t)(t0 + tq) * 64 + d;
#pragma unroll
  for (int c2 = 0; c2 < 32; ++c2) {
    float v = fmaxf(acc[c2] * S2[c2] + T2[c2], 0.f);
    y1u[ob + (size_t)c2 * 8192] = f2b(v);
    float s = v, q = v * v;
#pragma unroll
    for (int off = 32; off; off >>= 1) {
      s += __shfl_down(s, off);
      q += __shfl_down(q, off);
    }
    if (lane == 0) { reds[tq][c2] = s; redq[tq][c2] = q; }
  }
  __syncthreads();
  if (tid < 32) {
    float s = (reds[0][tid] + reds[1][tid]) + (reds[2][tid] + reds[3][tid]);
    float q = (redq[0][tid] + redq[1][tid]) + (redq[2][tid] + redq[3][tid]);
    ps1[(size_t)((b * 32 + tid) << 5) + blockIdx.y] = s;
    pss1[(size_t)((b * 32 + tid) << 5) + blockIdx.y] = q;
  }
}

__global__ __launch_bounds__(256) void k_red(
    const float* __restrict__ ps, const float* __restrict__ pss,
    float* __restrict__ stats, int npart, int nplanes)
{
  int p = blockIdx.x * 256 + threadIdx.x;
  if (p >= nplanes) return;
  float s = 0.f, q = 0.f;
  for (int j = 0; j < npart; ++j) {
    s += ps[(size_t)p * npart + j];
    q += pss[(size_t)p * npart + j];
  }
  stats[p] = s;
  stats[nplanes + p] = q;
}

template <typename T>
__global__ __launch_bounds__(256) void k_simam_t(
    T* __restrict__ buf, const float* __restrict__ stats, int nplanes)
{
  const int p = blockIdx.x, tid = threadIdx.x;
  T* base = buf + (size_t)p * 8192;
  const float s = stats[p], ss = stats[nplanes + p];
#pragma unroll 4
  for (int i = 0; i < 32; ++i) {
    int idx = tid + i * 256;
    float v = ld1(base + idx);
    st1(base + idx, simam_elem(v, s, ss));
  }
}

// --------------------------- CNN stage 2 (R2-verified) ----------------------
template <typename ZT>
__global__ __launch_bounds__(256) void k_conv2(
    const u16* __restrict__ y1u,
    const float* __restrict__ w2a, const float* __restrict__ b2a,
    const float* __restrict__ g2a, const float* __restrict__ bb2a,
    const float* __restrict__ m2a, const float* __restrict__ v2a,
    const float* __restrict__ w2b, const float* __restrict__ b2b,
    const float* __restrict__ g2b, const float* __restrict__ bb2b,
    const float* __restrict__ m2b, const float* __restrict__ v2b,
    ZT* __restrict__ z, float* __restrict__ ps2, float* __restrict__ pss2)
{
  __shared__ float y1s[32][4][66];
  __shared__ float a2[64][4][66];
  __shared__ float sA2a[64], sT2a[64], sA2b[64], sT2b[64];
  const int tid = threadIdx.x;
  const int t0 = blockIdx.x * 2, b = blockIdx.y;
  if (tid < 64) {
    float sa = g2a[tid] * rsqrtf(v2a[tid] + EPSBN);
    sA2a[tid] = sa;
    sT2a[tid] = (b2a[tid] - m2a[tid]) * sa + bb2a[tid];
    float sb = g2b[tid] * rsqrtf(v2b[tid] + EPSBN);
    sA2b[tid] = sb;
    sT2b[tid] = (b2b[tid] - m2b[tid]) * sb + bb2b[tid];
  }
  for (int i = tid; i < 32 * 4 * 66; i += 256) {
    int c1 = i / 264;
    int rr = i - c1 * 264;
    int r = rr / 66, cc = rr - r * 66;
    int t = t0 + r - 1, dd = cc - 1;
    float v = 0.f;
    if (t >= 0 && t < 128 && dd >= 0 && dd < 64)
      v = b2f(y1u[(size_t)(b * 32 + c1) * 8192 + t * 64 + dd]);
    y1s[c1][r][cc] = v;
  }
  __syncthreads();
  const int lane = tid & 63;
  const int c2base = __builtin_amdgcn_readfirstlane((int)(tid >> 6)) * 16;
#pragma unroll 1
  for (int i = 0; i < 16; ++i) {
    const int c2 = c2base + i;
    const float* wp = w2a + c2 * 32;  // uniform
    const float scl = sA2a[c2], off = sT2a[c2];
#pragma unroll 1
    for (int r = 0; r < 4; ++r) {
      for (int cc = lane; cc < 66; cc += 64) {
        float acc = 0.f;
#pragma unroll
        for (int c1 = 0; c1 < 32; ++c1) acc += y1s[c1][r][cc] * wp[c1];
        int t = t0 + r - 1, dd = cc - 1;
        float val = 0.f;
        if (t >= 0 && t < 128 && dd >= 0 && dd < 64)
          val = fmaxf(acc * scl + off, 0.f);
        a2[c2][r][cc] = val;
      }
    }
  }
  __syncthreads();
  const int d = tid & 63;
  const int gq = __builtin_amdgcn_readfirstlane((int)(tid >> 6));
  float acc[16][2];
#pragma unroll
  for (int i = 0; i < 16; ++i) { acc[i][0] = 0.f; acc[i][1] = 0.f; }
#pragma unroll 1
  for (int c1 = 0; c1 < 64; ++c1) {
    float a00 = a2[c1][0][d], a01 = a2[c1][0][d + 1], a02 = a2[c1][0][d + 2];
    float a10 = a2[c1][1][d], a11 = a2[c1][1][d + 1], a12 = a2[c1][1][d + 2];
    float a20 = a2[c1][2][d], a21 = a2[c1][2][d + 1], a22 = a2[c1][2][d + 2];
    float a30 = a2[c1][3][d], a31 = a2[c1][3][d + 1], a32 = a2[c1][3][d + 2];
#pragma unroll
    for (int i = 0; i < 16; ++i) {
      const float* wp = w2b + (size_t)((gq * 16 + i) * 64 + c1) * 9;  // uniform
      float w0 = wp[0], w1 = wp[1], w2 = wp[2];
      float w3 = wp[3], w4 = wp[4], w5 = wp[5];
      float w6 = wp[6], w7 = wp[7], w8 = wp[8];
      acc[i][0] += a00 * w0 + a01 * w1 + a02 * w2 + a10 * w3 + a11 * w4 +
                   a12 * w5 + a20 * w6 + a21 * w7 + a22 * w8;
      acc[i][1] += a10 * w0 + a11 * w1 + a12 * w2 + a20 * w3 + a21 * w4 +
                   a22 * w5 + a30 * w6 + a31 * w7 + a32 * w8;
    }
  }
#pragma unroll
  for (int i = 0; i < 16; ++i) {
    int c2 = gq * 16 + i;
    float sc = sA2b[c2], tb = sT2b[c2];
    float v0 = fmaxf(acc[i][0] * sc + tb, 0.f);
    float v1 = fmaxf(acc[i][1] * sc + tb, 0.f);
    size_t ob = (size_t)(b * 64 + c2) * 8192 + (size_t)t0 * 64 + d;
    st1(z + ob, v0);
    st1(z + ob + 64, v1);
    float s = v0 + v1, q = v0 * v0 + v1 * v1;
#pragma unroll
    for (int off = 32; off; off >>= 1) {
      s += __shfl_down(s, off);
      q += __shfl_down(q, off);
    }
    if (lane == 0) {
      ps2[(size_t)((b * 64 + c2) << 6) + blockIdx.x] = s;
      pss2[(size_t)((b * 64 + c2) << 6) + blockIdx.x] = q;
    }
  }
}

// --------------------------- weight bf16 prep -------------------------------
__global__ __launch_bounds__(256) void k_cvt(
    const float* __restrict__ src, u16* __restrict__ dst, int n)
{
  for (int i = blockIdx.x * 256 + threadIdx.x; i < n; i += gridDim.x * 256)
    dst[i] = f2b(src[i]);
}

// --------------------------- persistent LSTM -------------------------------
// Store-based grid barrier: block i stores epoch to slots[i] (no RMW).
// One wave spins reading all 512 slots (4 u64/lane) until min >= epoch.
__device__ __forceinline__ void gridbar(u32* slots, u32 ep) {
  asm volatile("s_waitcnt vmcnt(0) lgkmcnt(0)" ::: "memory");
  __syncthreads();  // every wave has drained its stores; block is done
  if (threadIdx.x == 0)
    __hip_atomic_store(&slots[blockIdx.x], ep, __ATOMIC_RELAXED,
                       __HIP_MEMORY_SCOPE_AGENT);
  if (threadIdx.x < 64) {
    const u64* base = (const u64*)slots + threadIdx.x * 4;
    for (;;) {
      bool ok = true;
#pragma unroll
      for (int j = 0; j < 4; ++j) {
        u64 v = __hip_atomic_load(base + j, __ATOMIC_RELAXED,
                                  __HIP_MEMORY_SCOPE_AGENT);
        ok = ok && ((u32)v >= ep) && ((u32)(v >> 32) >= ep);
      }
      if (__all((int)ok)) break;
      __builtin_amdgcn_s_sleep(2);
    }
  }
  __syncthreads();
  asm volatile("" ::: "memory");
}

// LDS xor swizzles (all preserve %4 alignment)
__device__ __forceinline__ int sw_q(int col) { return col ^ (((col >> 6) & 3) << 3); }
__device__ __forceinline__ int sw_r(int col) { return col ^ (((col >> 7) & 7) << 2); }
__device__ __forceinline__ int sw_g(int col) { return col ^ (((col >> 8) & 3) << 2); }
__device__ __forceinline__ int sw_h(int col) { return col ^ (((col >> 6) & 3) << 2); }

// q: xm[b,n] = 2*sigmoid(hsrc[b,:256].qw[n,:] + qb[n]) * xin[b,n]
// 512 blocks = 128 nt(32n) x 4 bt(32b). hsrc bf16 staged to LDS fp32.
template <typename ZT, bool FROMXM>
__device__ __forceinline__ void q_phase(
    const u16* __restrict__ qwb, const float* __restrict__ qb,
    const u16* __restrict__ hsrc, const ZT* __restrict__ zin,
    size_t zstride, const u16* __restrict__ xm_in, u16* __restrict__ xm_out,
    float* __restrict__ smem, int blk, int tid)
{
  const int nt = blk & 127, bt = blk >> 7;
  const int b0 = bt * 32;
  for (int i = tid; i < 2048; i += 512) {           // 32 rows x 64 quads
    int row = i >> 6, q4 = i & 63;
    float4 v = upk4(ld_sc_u64(hsrc + (size_t)(b0 + row) * 256 + q4 * 4));
    *(float4*)&smem[row * 258 + sw_q(q4 * 4)] = v;
  }
  __syncthreads();
  const int lane = tid & 63, w = tid >> 6;
  const int ns = lane & 15, ksub = lane >> 4;
  const int n0 = nt * 32 + ns * 2;
  const int bw = b0 + w * 4;
  float acc[2][4];
#pragma unroll
  for (int i = 0; i < 2; ++i)
#pragma unroll
    for (int j = 0; j < 4; ++j) acc[i][j] = 0.f;
  const u16* w0p = qwb + (size_t)n0 * 256 + ksub * 64;
  const u16* w1p = w0p + 256;
#pragma unroll 4
  for (int k = 0; k < 64; k += 4) {
    float4 wa = ldw4(w0p + k);
    float4 wb = ldw4(w1p + k);
    int sc = sw_q(ksub * 64 + k);
#pragma unroll
    for (int j = 0; j < 4; ++j) {
      float4 hv = *(const float4*)&smem[(w * 4 + j) * 258 + sc];
      acc[0][j] += dot4(wa, hv);
      acc[1][j] += dot4(wb, hv);
    }
  }
#pragma unroll
  for (int i = 0; i < 2; ++i)
#pragma unroll
    for (int j = 0; j < 4; ++j) {
      acc[i][j] += __shfl_xor(acc[i][j], 16);
      acc[i][j] += __shfl_xor(acc[i][j], 32);
    }
  if (ksub == 0) {
    float bq0 = qb[n0], bq1 = qb[n0 + 1];
#pragma unroll
    for (int j = 0; j < 4; ++j) {
      size_t bi = (size_t)(bw + j);
      float2 xv;
      if (FROMXM) xv = upk2(ld_sc_u32(xm_in + bi * 4096 + n0));
      else        xv = ld2p(zin + bi * zstride + n0);
      st_sc_u32(xm_out + bi * 4096 + n0,
                pk2(2.f * sigf(acc[0][j] + bq0) * xv.x,
                    2.f * sigf(acc[1][j] + bq1) * xv.y));
    }
  }
}

// r: hm[b,n] = 2*sigmoid(xm[b,:4096].rw[n,:] + rb[n]) * src[b,n]
// 512 blocks = 16 nt(16n) x 32 bt(4b). wave w -> n-pair {n0t+2w, +1}.
// lane: bl(4b) | np(2n) | ksub(8-way K-split). xm bf16 staged per 1024-chunk.
__device__ __forceinline__ void r_phase(
    const u16* __restrict__ rwb, const float* __restrict__ rb,
    const u16* __restrict__ srcb, const u16* __restrict__ xm,
    u16* __restrict__ hmb, float* __restrict__ smem, int blk, int tid)
{
  const int nt = blk & 15, bt = blk >> 4;
  const int n0t = nt * 16, b0 = bt * 4;
  const int lane = tid & 63, w = tid >> 6;
  const int bl = lane & 3, np = (lane >> 2) & 1, ksub = lane >> 3;
  const int n = n0t + 2 * w + np;
  float acc = 0.f;
  const u16* wr = rwb + (size_t)n * 4096;
#pragma unroll 1
  for (int c = 0; c < 4; ++c) {
    __syncthreads();
    for (int i = tid; i < 1024; i += 512) {          // 4 rows x 256 quads
      int row = i >> 8, qd = i & 255;
      float4 v = upk4(ld_sc_u64(xm + (size_t)(b0 + row) * 4096 + c * 1024 + qd * 4));
      *(float4*)&smem[row * 1040 + sw_r(qd * 4)] = v;
    }
    __syncthreads();
    const u16* wc = wr + c * 1024 + ksub * 128;
#pragma unroll 4
    for (int k = 0; k < 128; k += 4) {
      int sc = sw_r(ksub * 128 + k);
      float4 xv = *(const float4*)&smem[bl * 1040 + sc];
      float4 wv = ldw4(wc + k);
      acc += dot4(wv, xv);
    }
  }
  acc += __shfl_xor(acc, 8);
  acc += __shfl_xor(acc, 16);
  acc += __shfl_xor(acc, 32);
  float accp = __shfl_down(acc, 4);  // partner (np=1) value
  if (ksub == 0 && np == 0) {
    int idx = (b0 + bl) * 256 + n;   // n even
    float2 sv = upk2(ld_sc_u32(srcb + idx));
    st_sc_u32(hmb + idx, pk2(2.f * sigf(acc + rb[n]) * sv.x,
                             2.f * sigf(accp + rb[n + 1]) * sv.y));
  }
}

// gates: full-K (wih 4096 + whh 256) + fused cell update; h written bf16.
// 512 blocks = 16 kt(16kk) x 32 bt(4b). thread: ksub(4) | bp(2b) | row(64).
__device__ __forceinline__ void g_phase(
    const u16* __restrict__ wihb, const u16* __restrict__ whhb,
    const u16* __restrict__ xm, const u16* __restrict__ hmb,
    u16* __restrict__ hb, float& c_reg,
    float bi_i, float bi_f, float bi_g, float bi_o,
    float* __restrict__ smem, int blk, int tid)
{
  const int kt = blk & 15, bt = blk >> 4;
  const int b0 = bt * 4;
  const int ksub = tid & 3, bp = (tid >> 2) & 1, row = tid >> 3;
  const int gate = row >> 4, kkl = row & 15;
  const int grow = gate * 256 + kt * 16 + kkl;
  float* gatelds = smem + 8256;  // [64][4]
  float acc0 = 0.f, acc1 = 0.f;
  const u16* wr = wihb + (size_t)grow * 4096;
#pragma unroll 1
  for (int c = 0; c < 4; ++c) {
    __syncthreads();
    for (int i = tid; i < 1024; i += 512) {
      int r = i >> 8, qd = i & 255;
      float4 v = upk4(ld_sc_u64(xm + (size_t)(b0 + r) * 4096 + c * 1024 + qd * 4));
      *(float4*)&smem[r * 1040 + sw_g(qd * 4)] = v;
    }
    __syncthreads();
    const u16* wc = wr + c * 1024 + ksub * 256;
#pragma unroll 4
    for (int k = 0; k < 256; k += 4) {
      int sc = sw_g(ksub * 256 + k);
      float4 wv = ldw4(wc + k);
      float4 x0 = *(const float4*)&smem[(bp * 2 + 0) * 1040 + sc];
      float4 x1 = *(const float4*)&smem[(bp * 2 + 1) * 1040 + sc];
      acc0 += dot4(wv, x0);
      acc1 += dot4(wv, x1);
    }
  }
  // whh contribution (K=256 over hm bf16)
  __syncthreads();
  for (int i = tid; i < 256; i += 512) {
    int r = i >> 6, q4 = i & 63;
    float4 v = upk4(ld_sc_u64(hmb + (size_t)(b0 + r) * 256 + q4 * 4));
    *(float4*)&smem[r * 264 + sw_h(q4 * 4)] = v;
  }
  __syncthreads();
  {
    const u16* vr = whhb + (size_t)grow * 256 + ksub * 64;
#pragma unroll 4
    for (int k = 0; k < 64; k += 4) {
      int sc = sw_h(ksub * 64 + k);
      float4 wv = ldw4(vr + k);
      float4 x0 = *(const float4*)&smem[(bp * 2 + 0) * 264 + sc];
      float4 x1 = *(const float4*)&smem[(bp * 2 + 1) * 264 + sc];
      acc0 += dot4(wv, x0);
      acc1 += dot4(wv, x1);
    }
  }
  acc0 += __shfl_xor(acc0, 1);
  acc0 += __shfl_xor(acc0, 2);
  acc1 += __shfl_xor(acc1, 1);
  acc1 += __shfl_xor(acc1, 2);
  __syncthreads();
  if (ksub == 0) {
    gatelds[row * 4 + bp * 2 + 0] = acc0;
    gatelds[row * 4 + bp * 2 + 1] = acc1;
  }
  __syncthreads();
  if (tid < 64) {
    int kk2 = tid & 15, blc = tid >> 4;
    float gi = gatelds[(kk2) * 4 + blc] + bi_i;
    float gf = gatelds[(16 + kk2) * 4 + blc] + bi_f;
    float gg = gatelds[(32 + kk2) * 4 + blc] + bi_g;
    float go = gatelds[(48 + kk2) * 4 + blc] + bi_o;
    float cn = sigf(gf) * c_reg + sigf(gi) * tanhf(gg);
    c_reg = cn;
    u16 me = f2b(sigf(go) * tanhf(cn));
    u32 partner = __shfl_down((int)(u32)me, 1);
    if ((tid & 1) == 0)  // kk2 even; pair with kk2+1 (same blc)
      st_sc_u32(hb + (b0 + blc) * 256 + kt * 16 + kk2,
                (u32)me | (partner << 16));
  }
}

template <typename ZT>
__global__ __launch_bounds__(512, 4) void k_lstm(
    const ZT* __restrict__ z,
    const u16* __restrict__ q0wb, const float* __restrict__ q0b,
    const u16* __restrict__ r0wb, const float* __restrict__ r0b,
    const u16* __restrict__ q1wb, const float* __restrict__ q1b,
    const u16* __restrict__ r1wb, const float* __restrict__ r1b,
    const u16* __restrict__ q2wb, const float* __restrict__ q2b,
    const u16* __restrict__ r2wb, const float* __restrict__ r2b,
    const u16* __restrict__ wihb, const u16* __restrict__ whhb,
    const float* __restrict__ bih, const float* __restrict__ bhh,
    const float* __restrict__ fcw, const float* __restrict__ fcb,
    u16* __restrict__ xm, u16* __restrict__ hb, u16* __restrict__ hmb,
    u32* __restrict__ slots, float* __restrict__ out)
{
  __shared__ float smem[8520];
  const int blk = blockIdx.x, tid = threadIdx.x;
  float bi_i = 0.f, bi_f = 0.f, bi_g = 0.f, bi_o = 0.f, c_reg = 0.f;
  {
    const int kt = blk & 15;
    if (tid < 64) {
      int gk = kt * 16 + (tid & 15);
      bi_i = bih[gk] + bhh[gk];
      bi_f = bih[gk + 256] + bhh[gk + 256];
      bi_g = bih[gk + 512] + bhh[gk + 512];
      bi_o = bih[gk + 768] + bhh[gk + 768];
    }
  }
  u32 ep = 0;
#pragma unroll 1
  for (int t = 0; t < 128; ++t) {
    q_phase<ZT, false>(q0wb, q0b, hb, z + (size_t)t * 4096, 524288, xm, xm,
                       smem, blk, tid);
    gridbar(slots, ++ep);
    r_phase(r0wb, r0b, hb, xm, hmb, smem, blk, tid);
    gridbar(slots, ++ep);
    q_phase<ZT, true>(q1wb, q1b, hmb, (const ZT*)0, 0, xm, xm, smem, blk, tid);
    gridbar(slots, ++ep);
    r_phase(r1wb, r1b, hmb, xm, hmb, smem, blk, tid);
    gridbar(slots, ++ep);
    q_phase<ZT, true>(q2wb, q2b, hmb, (const ZT*)0, 0, xm, xm, smem, blk, tid);
    gridbar(slots, ++ep);
    r_phase(r2wb, r2b, hmb, xm, hmb, smem, blk, tid);
    gridbar(slots, ++ep);
    g_phase(wihb, whhb, xm, hmb, hb, c_reg, bi_i, bi_f, bi_g, bi_o,
            smem, blk, tid);
    gridbar(slots, ++ep);
  }
  if (blk < 128 && tid < 5) {
    float acc = fcb[tid];
    const u16* hr = hb + blk * 256;
    const float* wr = fcw + (size_t)tid * 256;
    for (int k = 0; k < 256; k += 2) {
      float2 hv = upk2(ld_sc_u32(hr + k));
      acc += hv.x * wr[k] + hv.y * wr[k + 1];
    }
    out[blk * 5 + tid] = acc;
  }
}

__global__ __launch_bounds__(256) void k_report(float* out, float v, int n) {
  int i = blockIdx.x * 256 + threadIdx.x;
  if (i < n) out[i] = v;
}

// ---------------------------------------------------------------------------
struct Net {
  const float *x;
  const float *c1a_w, *c1a_b, *g1a, *b1a, *m1a, *v1a;
  const float *c1b_w, *c1b_b, *g1b, *b1b, *m1b, *v1b;
  const float *c2a_w, *c2a_b, *g2a, *b2a, *m2a, *v2a;
  const float *c2b_w, *c2b_b, *g2b, *b2b, *m2b, *v2b;
  const float *qw[3], *qb[3], *rw[3], *rb[3];
  const float *wih, *whh, *bih, *bhh, *fcw, *fcb;
};

template <typename ZT>
static void run_all(const Net& p, ZT* z, u16* y1u, char* scr,
                    float* ps1, float* pss1, float* st1v,
                    float* ps2, float* pss2, float* st2v,
                    float* out, hipStream_t stream)
{
  u16* xm   = (u16*)scr;                  // 1 MB
  u16* hb   = (u16*)(scr + 0x100000);     // 64 KB
  u16* hmb  = (u16*)(scr + 0x110000);     // 64 KB
  u32* slots = (u32*)(scr + 0x120000);    // 2 KB (512 slots)
  u16* qwb[3] = {(u16*)(scr + 0x200000), (u16*)(scr + 0x400000),
                 (u16*)(scr + 0x600000)};
  u16* rwb[3] = {(u16*)(scr + 0x800000), (u16*)(scr + 0xA00000),
                 (u16*)(scr + 0xC00000)};
  u16* wihb = (u16*)(scr + 0xE00000);     // 8 MB
  u16* whhb = (u16*)(scr + 0x1600000);    // 512 KB

  k_conv1<<<dim3(128, 32), 256, 0, stream>>>(p.x, p.c1a_w, p.c1a_b, p.g1a,
      p.b1a, p.m1a, p.v1a, p.c1b_w, p.c1b_b, p.g1b, p.b1b, p.m1b, p.v1b,
      y1u, ps1, pss1);
  k_red<<<16, 256, 0, stream>>>(ps1, pss1, st1v, 32, 4096);
  k_simam_t<u16><<<4096, 256, 0, stream>>>(y1u, st1v, 4096);
  k_conv2<ZT><<<dim3(64, 128), 256, 0, stream>>>(y1u, p.c2a_w, p.c2a_b, p.g2a,
      p.b2a, p.m2a, p.v2a, p.c2b_w, p.c2b_b, p.g2b, p.b2b, p.m2b, p.v2b,
      z, ps2, pss2);
  k_red<<<32, 256, 0, stream>>>(ps2, pss2, st2v, 64, 8192);
  k_simam_t<ZT><<<8192, 256, 0, stream>>>(z, st2v, 8192);

  // weight bf16 prep (scr overlays y1u, dead after conv2 -> must follow it)
  for (int i = 0; i < 3; ++i) {
    k_cvt<<<1024, 256, 0, stream>>>(p.qw[i], qwb[i], 1048576);
    k_cvt<<<1024, 256, 0, stream>>>(p.rw[i], rwb[i], 1048576);
  }
  k_cvt<<<2048, 256, 0, stream>>>(p.wih, wihb, 4194304);
  k_cvt<<<256, 256, 0, stream>>>(p.whh, whhb, 262144);

  hipMemsetAsync(hb, 0, 65536, stream);   // h(t=0) = 0 (bf16 zero == 0x0000)
  hipMemsetAsync(slots, 0, 2048, stream);

  k_lstm<ZT><<<512, 512, 0, stream>>>(z,
      qwb[0], p.qb[0], rwb[0], p.rb[0],
      qwb[1], p.qb[1], rwb[1], p.rb[1],
      qwb[2], p.qb[2], rwb[2], p.rb[2],
      wihb, whhb, p.bih, p.bhh, p.fcw, p.fcb,
      xm, hb, hmb, slots, out);
}

extern "C" void kernel_launch(void* const* d_in, const int* in_sizes, int n_in,
                              void* d_out, int out_size, void* d_ws, size_t ws_size,
                              hipStream_t stream)
{
  (void)in_sizes; (void)n_in;
  Net p;
  p.x = (const float*)d_in[0];
  p.c1a_w = (const float*)d_in[1];  p.c1a_b = (const float*)d_in[2];
  p.g1a = (const float*)d_in[3];    p.b1a = (const float*)d_in[4];
  p.m1a = (const float*)d_in[5];    p.v1a = (const float*)d_in[6];
  p.c1b_w = (const float*)d_in[7];  p.c1b_b = (const float*)d_in[8];
  p.g1b = (const float*)d_in[9];    p.b1b = (const float*)d_in[10];
  p.m1b = (const float*)d_in[11];   p.v1b = (const float*)d_in[12];
  p.c2a_w = (const float*)d_in[13]; p.c2a_b = (const float*)d_in[14];
  p.g2a = (const float*)d_in[15];   p.b2a = (const float*)d_in[16];
  p.m2a = (const float*)d_in[17];   p.v2a = (const float*)d_in[18];
  p.c2b_w = (const float*)d_in[19]; p.c2b_b = (const float*)d_in[20];
  p.g2b = (const float*)d_in[21];   p.b2b = (const float*)d_in[22];
  p.m2b = (const float*)d_in[23];   p.v2b = (const float*)d_in[24];
  for (int i = 0; i < 3; ++i) {
    p.qw[i] = (const float*)d_in[25 + 4 * i];
    p.qb[i] = (const float*)d_in[26 + 4 * i];
    p.rw[i] = (const float*)d_in[27 + 4 * i];
    p.rb[i] = (const float*)d_in[28 + 4 * i];
  }
  p.wih = (const float*)d_in[37]; p.whh = (const float*)d_in[38];
  p.bih = (const float*)d_in[39]; p.bhh = (const float*)d_in[40];
  p.fcw = (const float*)d_in[41]; p.fcb = (const float*)d_in[42];
  float* out = (float*)d_out;
  char* base = (char*)d_ws;

  const size_t ZB_F32 = 268435456, ZB_BF16 = 134217728, Y1B = 67108864;
  const size_t STATS = 1048576 * 2 + 65536 + 2097152 * 2 + 65536;
  const size_t HI_NEED = ZB_F32 + Y1B + STATS;   // ~326 MiB
  const size_t LO_NEED = ZB_BF16 + Y1B + STATS;  // ~198 MiB

  if (ws_size >= HI_NEED) {
    float* z = (float*)base;
    u16* y1u = (u16*)(base + ZB_F32);
    char* scr = base + ZB_F32;  // overlays y1u (dead after conv2)
    char* sb = base + ZB_F32 + Y1B;
    run_all<float>(p, z, y1u, scr,
                   (float*)sb, (float*)(sb + 1048576), (float*)(sb + 2097152),
                   (float*)(sb + 2162688), (float*)(sb + 4259840),
                   (float*)(sb + 6356992), out, stream);
  } else if (ws_size >= LO_NEED) {
    u16* z = (u16*)base;
    u16* y1u = (u16*)(base + ZB_BF16);
    char* scr = base + ZB_BF16;  // overlays y1u (dead after conv2)
    char* sb = base + ZB_BF16 + Y1B;
    run_all<u16>(p, z, y1u, scr,
                 (float*)sb, (float*)(sb + 1048576), (float*)(sb + 2097152),
                 (float*)(sb + 2162688), (float*)(sb + 4259840),
                 (float*)(sb + 6356992), out, stream);
  } else {
    k_report<<<3, 256, 0, stream>>>(out, (float)(ws_size >> 20), out_size);
  }
}